// Round 25
// baseline (6474.526 us; speedup 1.0000x reference)
//
#include <hip/hip_runtime.h>

// DownSampling: B=16, N=16384, C=128, M=4096. f32 in/out.
// LOCKED ORACLE SEMANTICS (R14, absmax==0): per point,
//   dx=px-cx; dy=py-cy; dz=pz-cz;
//   d = fma(dz,dz, fma(dx,dx, rn(dy*dy)))   [XLA-GPU tree contraction]
//   dist = min(dist, d); argmax = (max value, MIN index).
// R25: single-barrier zero-atomic tail. Each wave computes its OWN
// (wavemax, wave-arg-idx) BEFORE the barrier (all-DPP reduce -> readlane ->
// ballot -> lowest matching lane scans its 16 slots) and stores the pair to
// its private ring slot (plain LDS stores). ONE __syncthreads; then all
// waves join 16 (val,idx) pairs with the R17-proven 4-step DPP
// (max,min-idx) reduce. Lower lane => lower global idx (contiguous
// ownership), so the join reproduces the global first-index argmax exactly.
// B2, widx and atomicMin are gone. Distance phase + LDS coord cache = R19.
#define B_   16
#define N_   16384
#define C_   128
#define M_   4096
#define TPB  1024
#define PPT  16    // points per thread: TPB*PPT == N_
#define NC   10880 // points with coords cached in LDS (3*NC*4 = 130560 B)

#define DPP_QUAD_XOR1   0xB1   // quad_perm [1,0,3,2]
#define DPP_QUAD_XOR2   0x4E   // quad_perm [2,3,0,1]
#define DPP_HALF_MIRROR 0x141  // mirror within 8-lane half-rows
#define DPP_ROW_MIRROR  0x140  // mirror within 16-lane rows
#define DPP_BCAST15     0x142  // lane15 -> 16..31, lane47 -> 48..63
#define DPP_BCAST31     0x143  // lane31 -> 32..63

// value-only max join via DPP (VALU pipe) — R20/R21-proven
#define VMAX_DPP(V, CTRL) do{                                                      \
    float _o = __int_as_float(__builtin_amdgcn_update_dpp(                         \
        __float_as_int(V), __float_as_int(V), (CTRL), 0xF, 0xF, false));           \
    (V) = fmaxf((V), _o);                                                          \
}while(0)

// (max value, min index) join via DPP — R17-proven (bit-exact pass)
#define AMAX_DPP(V, I, CTRL) do{                                                    \
    float _ov = __int_as_float(__builtin_amdgcn_mov_dpp(__float_as_int(V),          \
                                                        (CTRL), 0xF, 0xF, 0));     \
    int   _oi = __builtin_amdgcn_mov_dpp((I), (CTRL), 0xF, 0xF, 0);                 \
    bool _tk = (_ov > (V)) || ((_ov == (V)) && (_oi < (I)));                        \
    (V) = _tk ? _ov : (V);  (I) = _tk ? _oi : (I);                                  \
}while(0)

__global__ __launch_bounds__(TPB, 4) void fps_kernel(const float* __restrict__ xyz,
                                                     int* __restrict__ idx_out)
{
    const int b = blockIdx.x;
    const int t = threadIdx.x;
    const int wid  = t >> 6;
    const int lane = t & 63;
    const float* xb = xyz + (size_t)b * 3 * N_;

    extern __shared__ float smem[];          // dynamic: coord cache
    float* cX = smem;
    float* cY = smem + NC;
    float* cZ = smem + 2 * NC;

    float px[PPT], py[PPT], pz[PPT], dist[PPT];

    // Load 16 consecutive points per thread (float4-vectorized, coalesced).
    {
        const float4* x4 = reinterpret_cast<const float4*>(xb);
        const float4* y4 = reinterpret_cast<const float4*>(xb + N_);
        const float4* z4 = reinterpret_cast<const float4*>(xb + 2 * N_);
        #pragma unroll
        for (int q = 0; q < 4; ++q) {
            float4 vx = x4[t * 4 + q];
            float4 vy = y4[t * 4 + q];
            float4 vz = z4[t * 4 + q];
            px[q*4+0] = vx.x; px[q*4+1] = vx.y; px[q*4+2] = vx.z; px[q*4+3] = vx.w;
            py[q*4+0] = vy.x; py[q*4+1] = vy.y; py[q*4+2] = vy.z; py[q*4+3] = vy.w;
            pz[q*4+0] = vz.x; pz[q*4+1] = vz.y; pz[q*4+2] = vz.z; pz[q*4+3] = vz.w;
        }
    }
    #pragma unroll
    for (int i = 0; i < PPT; ++i) dist[i] = 1e10f;  // BIG sentinel

    // Fill LDS coord cache (one-time; visible by first use via iter-1 barrier).
    for (int p = t; p < NC; p += TPB) {
        cX[p] = xb[p];
        cY[p] = xb[N_ + p];
        cZ[p] = xb[2 * N_ + p];
    }

    __shared__ float lv[2][16];   // per-wave (value, index) partials,
    __shared__ int   li[2][16];   // double-buffered (write buf != read buf)

    if (t == 0) idx_out[b * M_ + 0] = 0;   // deterministic start at index 0

    // First centroid = point 0.
    float cx = xb[0], cy = xb[N_], cz = xb[2 * N_];

    for (int m = 1; m < M_; ++m) {
        const int buf = m & 1;

        // ---- a: distance update (locked semantics) + value max (max3 pairs)
        float vmax = -1.0f;
        #pragma unroll
        for (int i = 0; i < PPT; i += 2) {
            float dx0 = __fsub_rn(px[i], cx);
            float dy0 = __fsub_rn(py[i], cy);
            float dz0 = __fsub_rn(pz[i], cz);
            float d0  = fmaf(dz0, dz0, fmaf(dx0, dx0, __fmul_rn(dy0, dy0)));
            float n0  = fminf(dist[i], d0);
            dist[i] = n0;
            float dx1 = __fsub_rn(px[i+1], cx);
            float dy1 = __fsub_rn(py[i+1], cy);
            float dz1 = __fsub_rn(pz[i+1], cz);
            float d1  = fmaf(dz1, dz1, fmaf(dx1, dx1, __fmul_rn(dy1, dy1)));
            float n1  = fminf(dist[i+1], d1);
            dist[i+1] = n1;
            vmax = fmaxf(fmaxf(vmax, n0), n1);   // fuses to v_max3_f32 (exact)
        }
        const float lmax = vmax;   // per-thread max

        // ---- b: all-DPP wave value-reduce; lane 63 ends with the wave max
        VMAX_DPP(vmax, DPP_QUAD_XOR1);
        VMAX_DPP(vmax, DPP_QUAD_XOR2);
        VMAX_DPP(vmax, DPP_HALF_MIRROR);
        VMAX_DPP(vmax, DPP_ROW_MIRROR);
        VMAX_DPP(vmax, DPP_BCAST15);
        VMAX_DPP(vmax, DPP_BCAST31);
        const float wmax = __int_as_float(
            __builtin_amdgcn_readlane(__float_as_int(vmax), 63));

        // ---- c: lowest matching lane computes the wave's arg-index and posts
        //         (wmax, idx) to this wave's private ring slot (plain stores).
        unsigned long long mask = __ballot(lmax == wmax);
        const int first = (int)(__ffsll((long long)mask) - 1);
        if (lane == first) {
            int cand = 0;
            #pragma unroll
            for (int i = PPT - 1; i >= 0; --i)      // descending: first slot wins
                cand = (dist[i] == wmax) ? i : cand;
            lv[buf][wid] = wmax;
            li[buf][wid] = t * PPT + cand;
        }
        __syncthreads();   // the ONLY barrier per iteration

        // ---- d: block (max value, min index) join over 16 wave pairs (DPP)
        float v2 = (lane < 16) ? lv[buf][lane] : -1.0f;
        int   gi = (lane < 16) ? li[buf][lane] : 0x7fffffff;
        AMAX_DPP(v2, gi, DPP_QUAD_XOR1);
        AMAX_DPP(v2, gi, DPP_QUAD_XOR2);
        AMAX_DPP(v2, gi, DPP_HALF_MIRROR);
        AMAX_DPP(v2, gi, DPP_ROW_MIRROR);
        const int j = __builtin_amdgcn_readfirstlane(gi);

        if (t == 0) idx_out[b * M_ + m] = j;

        // ---- e: reload centroid (LDS-cached or L2)
        if (j < NC) {   // uniform scalar branch; ds_read broadcast (~70cyc)
            cx = cX[j];
            cy = cY[j];
            cz = cZ[j];
        } else {        // fallback: L2 loads (~200cyc), 34% of iterations
            cx = xb[j];
            cy = xb[N_ + j];
            cz = xb[2 * N_ + j];
        }
    }
}

// -------------------------------------------------------------------------
// Gather kernel: one block per (batch, output row). Rows 0..2 = xyz, 3..130 =
// feature channels. Raw f32 passthrough of gathered values.
// -------------------------------------------------------------------------
__global__ void gather_kernel(const float* __restrict__ xyz,
                              const float* __restrict__ feat,
                              const int*   __restrict__ idx,
                              float*       __restrict__ out)
{
    const int blk = blockIdx.x;
    const int b = blk / (3 + C_);
    const int r = blk % (3 + C_);
    const int* idb = idx + b * M_;

    if (r < 3) {
        const float* src = xyz + ((size_t)b * 3 + r) * N_;
        float*       dst = out + ((size_t)b * 3 + r) * M_;
        for (int m = threadIdx.x; m < M_; m += blockDim.x)
            dst[m] = src[idb[m]];
    } else {
        const int c = r - 3;
        const float* src = feat + ((size_t)b * C_ + c) * N_;
        float*       dst = out + (size_t)B_ * 3 * M_ + ((size_t)b * C_ + c) * M_;
        for (int m = threadIdx.x; m < M_; m += blockDim.x)
            dst[m] = src[idb[m]];
    }
}

extern "C" void kernel_launch(void* const* d_in, const int* in_sizes, int n_in,
                              void* d_out, int out_size, void* d_ws, size_t ws_size,
                              hipStream_t stream)
{
    const float* xyz  = (const float*)d_in[0];   // [16, 3, 16384] f32
    const float* feat = (const float*)d_in[1];   // [16, 128, 16384] f32
    float* out = (float*)d_out;                  // [16*3*4096] + [16*128*4096] f32
    int*   idx = (int*)d_ws;                     // [16, 4096] int32 scratch

    const size_t dyn_lds = (size_t)3 * NC * sizeof(float);   // 130560 B
    fps_kernel<<<dim3(B_), dim3(TPB), dyn_lds, stream>>>(xyz, idx);
    gather_kernel<<<dim3(B_ * (3 + C_)), dim3(256), 0, stream>>>(xyz, feat, idx, out);
}

// Round 26
// 5606.324 us; speedup vs baseline: 1.1549x; 1.1549x over previous
//
#include <hip/hip_runtime.h>

// DownSampling: B=16, N=16384, C=128, M=4096. f32 in/out.
// LOCKED ORACLE SEMANTICS (R14, absmax==0): per point,
//   dx=px-cx; dy=py-cy; dz=pz-cz;
//   d = fma(dz,dz, fma(dx,dx, rn(dy*dy)))   [XLA-GPU tree contraction]
//   dist = min(dist, d); argmax = (max value, MIN index).
// R26: wave-count midpoint. TPB=512, PPT=32 (8 waves, 2/SIMD): same
// distance-phase issue cycles per SIMD as R19, but barriers sync 8 waves
// (not 16), block reduce = 8 partials (3 DPP steps), half the per-block
// bookkeeping. State 128 floats + temps < 256-VGPR cap @ 2 waves/SIMD
// (R23's spill mode avoided). Tail structure = R19 verbatim otherwise.
#define B_   16
#define N_   16384
#define C_   128
#define M_   4096
#define TPB  512
#define PPT  32    // points per thread: TPB*PPT == N_
#define NC   10880 // points with coords cached in LDS (3*NC*4 = 130560 B)

#define DPP_QUAD_XOR1   0xB1   // quad_perm [1,0,3,2]
#define DPP_QUAD_XOR2   0x4E   // quad_perm [2,3,0,1]
#define DPP_HALF_MIRROR 0x141  // mirror within 8-lane half-rows
#define DPP_ROW_MIRROR  0x140  // mirror within 16-lane rows
#define SWZ_XOR16       0x401F // BitMode xor-16 within 32-lane groups

// value-only max join via DPP (VALU pipe) — R19-proven
#define VMAX_DPP(V, CTRL) do{                                                      \
    float _o = __int_as_float(__builtin_amdgcn_mov_dpp(__float_as_int(V),          \
                                                       (CTRL), 0xF, 0xF, 0));      \
    (V) = fmaxf((V), _o);                                                          \
}while(0)

// value-only max join via ds_swizzle xor pattern — R19-proven
#define VMAX_SWZ(V, PAT) do{                                                       \
    float _o = __int_as_float(__builtin_amdgcn_ds_swizzle(__float_as_int(V), PAT));\
    (V) = fmaxf((V), _o);                                                          \
}while(0)

__global__ __launch_bounds__(TPB, 2) void fps_kernel(const float* __restrict__ xyz,
                                                     int* __restrict__ idx_out)
{
    const int b = blockIdx.x;
    const int t = threadIdx.x;
    const int wid  = t >> 6;   // 0..7
    const int lane = t & 63;
    const float* xb = xyz + (size_t)b * 3 * N_;

    extern __shared__ float smem[];          // dynamic: coord cache
    float* cX = smem;
    float* cY = smem + NC;
    float* cZ = smem + 2 * NC;

    float px[PPT], py[PPT], pz[PPT], dist[PPT];

    // Load 32 consecutive points per thread (8 float4s).
    {
        const float4* x4 = reinterpret_cast<const float4*>(xb);
        const float4* y4 = reinterpret_cast<const float4*>(xb + N_);
        const float4* z4 = reinterpret_cast<const float4*>(xb + 2 * N_);
        #pragma unroll
        for (int q = 0; q < 8; ++q) {
            float4 vx = x4[t * 8 + q];
            float4 vy = y4[t * 8 + q];
            float4 vz = z4[t * 8 + q];
            px[q*4+0] = vx.x; px[q*4+1] = vx.y; px[q*4+2] = vx.z; px[q*4+3] = vx.w;
            py[q*4+0] = vy.x; py[q*4+1] = vy.y; py[q*4+2] = vy.z; py[q*4+3] = vy.w;
            pz[q*4+0] = vz.x; pz[q*4+1] = vz.y; pz[q*4+2] = vz.z; pz[q*4+3] = vz.w;
        }
    }
    #pragma unroll
    for (int i = 0; i < PPT; ++i) dist[i] = 1e10f;  // BIG sentinel

    // Fill LDS coord cache (one-time; visible by first use via iter-1 barriers).
    for (int p = t; p < NC; p += TPB) {
        cX[p] = xb[p];
        cY[p] = xb[N_ + p];
        cZ[p] = xb[2 * N_ + p];
    }

    __shared__ float lv[4][8];    // per-wave value partials (4-ring)
    __shared__ int   widx[4];     // winning-index word per ring

    if (t < 4) widx[t] = 0x7fffffff;   // init rings; visible after B1(m=1)

    if (t == 0) idx_out[b * M_ + 0] = 0;   // deterministic start at index 0

    // First centroid = point 0.
    float cx = xb[0], cy = xb[N_], cz = xb[2 * N_];

    for (int m = 1; m < M_; ++m) {
        const int buf = m & 3;

        // ---- a: distance update (locked semantics) + value max (max3 pairs)
        float vmax = -1.0f;
        #pragma unroll
        for (int i = 0; i < PPT; i += 2) {
            float dx0 = __fsub_rn(px[i], cx);
            float dy0 = __fsub_rn(py[i], cy);
            float dz0 = __fsub_rn(pz[i], cz);
            float d0  = fmaf(dz0, dz0, fmaf(dx0, dx0, __fmul_rn(dy0, dy0)));
            float n0  = fminf(dist[i], d0);
            dist[i] = n0;
            float dx1 = __fsub_rn(px[i+1], cx);
            float dy1 = __fsub_rn(py[i+1], cy);
            float dz1 = __fsub_rn(pz[i+1], cz);
            float d1  = fmaf(dz1, dz1, fmaf(dx1, dx1, __fmul_rn(dy1, dy1)));
            float n1  = fminf(dist[i+1], d1);
            dist[i+1] = n1;
            vmax = fmaxf(fmaxf(vmax, n0), n1);   // fuses to v_max3_f32 (exact)
        }
        const float lmax = vmax;   // pre-reduce local max for match test

        // ---- b: wave value-reduce (4 DPP + xor16 swizzle + xor32 shfl)
        VMAX_DPP(vmax, DPP_QUAD_XOR1);
        VMAX_DPP(vmax, DPP_QUAD_XOR2);
        VMAX_DPP(vmax, DPP_HALF_MIRROR);
        VMAX_DPP(vmax, DPP_ROW_MIRROR);
        VMAX_SWZ(vmax, SWZ_XOR16);
        vmax = fmaxf(vmax, __shfl_xor(vmax, 32));

        // ---- c: publish wave partial; reset ring for iter m+2 (barrier-safe)
        if (lane == 0) lv[buf][wid] = vmax;
        if (t == 0) widx[(m + 2) & 3] = 0x7fffffff;
        __syncthreads();   // B1

        // ---- d: block value-reduce (8 partials; 3 DPP steps cover 8 lanes)
        float v2 = (lane < 8) ? lv[buf][lane] : -1.0f;
        VMAX_DPP(v2, DPP_QUAD_XOR1);
        VMAX_DPP(v2, DPP_QUAD_XOR2);
        VMAX_DPP(v2, DPP_HALF_MIRROR);
        const float bmax = __int_as_float(
            __builtin_amdgcn_readfirstlane(__float_as_int(v2)));

        // ---- e: rare index-find (only matching thread(s); waves skip via execz)
        if (lmax == bmax) {
            int cand = 0;
            #pragma unroll
            for (int i = PPT - 1; i >= 0; --i)      // descending: smallest slot wins
                cand = (dist[i] == bmax) ? i : cand;
            atomicMin(&widx[buf], t * PPT + cand);  // global MIN index (tie-break)
        }
        __syncthreads();   // B2

        // ---- f: read winner, emit, reload centroid (LDS-cached or VMEM)
        const int j = __builtin_amdgcn_readfirstlane(widx[buf]);
        if (t == 0) idx_out[b * M_ + m] = j;
        if (j < NC) {   // uniform scalar branch; ds_read broadcast (~70cyc)
            cx = cX[j];
            cy = cY[j];
            cz = cZ[j];
        } else {        // fallback: L2 loads (~200cyc), 34% of iterations
            cx = xb[j];
            cy = xb[N_ + j];
            cz = xb[2 * N_ + j];
        }
    }
}

// -------------------------------------------------------------------------
// Gather kernel: one block per (batch, output row). Rows 0..2 = xyz, 3..130 =
// feature channels. Raw f32 passthrough of gathered values.
// -------------------------------------------------------------------------
__global__ void gather_kernel(const float* __restrict__ xyz,
                              const float* __restrict__ feat,
                              const int*   __restrict__ idx,
                              float*       __restrict__ out)
{
    const int blk = blockIdx.x;
    const int b = blk / (3 + C_);
    const int r = blk % (3 + C_);
    const int* idb = idx + b * M_;

    if (r < 3) {
        const float* src = xyz + ((size_t)b * 3 + r) * N_;
        float*       dst = out + ((size_t)b * 3 + r) * M_;
        for (int m = threadIdx.x; m < M_; m += blockDim.x)
            dst[m] = src[idb[m]];
    } else {
        const int c = r - 3;
        const float* src = feat + ((size_t)b * C_ + c) * N_;
        float*       dst = out + (size_t)B_ * 3 * M_ + ((size_t)b * C_ + c) * M_;
        for (int m = threadIdx.x; m < M_; m += blockDim.x)
            dst[m] = src[idb[m]];
    }
}

extern "C" void kernel_launch(void* const* d_in, const int* in_sizes, int n_in,
                              void* d_out, int out_size, void* d_ws, size_t ws_size,
                              hipStream_t stream)
{
    const float* xyz  = (const float*)d_in[0];   // [16, 3, 16384] f32
    const float* feat = (const float*)d_in[1];   // [16, 128, 16384] f32
    float* out = (float*)d_out;                  // [16*3*4096] + [16*128*4096] f32
    int*   idx = (int*)d_ws;                     // [16, 4096] int32 scratch

    const size_t dyn_lds = (size_t)3 * NC * sizeof(float);   // 130560 B
    fps_kernel<<<dim3(B_), dim3(TPB), dyn_lds, stream>>>(xyz, idx);
    gather_kernel<<<dim3(B_ * (3 + C_)), dim3(256), 0, stream>>>(xyz, feat, idx, out);
}

// Round 27
// 5136.491 us; speedup vs baseline: 1.2605x; 1.0915x over previous
//
#include <hip/hip_runtime.h>

// DownSampling: B=16, N=16384, C=128, M=4096. f32 in/out.
// FINAL (= R19, session best 5047us). LOCKED ORACLE SEMANTICS (R14,
// absmax==0): per point,
//   dx=px-cx; dy=py-cy; dz=pz-cz;
//   d = fma(dz,dz, fma(dx,dx, rn(dy*dy)))   [XLA-GPU tree contraction]
//   dist = min(dist, d); argmax = (max value, MIN index), first-index ties.
// Structure: 1 block/batch, 16 waves x 16 pts in registers; value-only max
// in the inner loop (v_max3 pairs); DPP+swizzle wave reduce; 2 barriers with
// rare-thread index-find via LDS atomicMin (4-ring, race-free); 127.5KB LDS
// coord cache for the centroid reload. Established by R15-R26 sweeps:
// scalar>packed, 16 waves>8>4, this tail > all single-barrier variants.
#define B_   16
#define N_   16384
#define C_   128
#define M_   4096
#define TPB  1024
#define PPT  16    // points per thread: TPB*PPT == N_
#define NC   10880 // points with coords cached in LDS (3*NC*4 = 130560 B)

#define DPP_QUAD_XOR1   0xB1   // quad_perm [1,0,3,2]
#define DPP_QUAD_XOR2   0x4E   // quad_perm [2,3,0,1]
#define DPP_HALF_MIRROR 0x141  // mirror within 8-lane half-rows
#define DPP_ROW_MIRROR  0x140  // mirror within 16-lane rows
#define SWZ_XOR16       0x401F // BitMode xor-16 within 32-lane groups

// value-only max join via DPP (VALU pipe)
#define VMAX_DPP(V, CTRL) do{                                                      \
    float _o = __int_as_float(__builtin_amdgcn_mov_dpp(__float_as_int(V),          \
                                                       (CTRL), 0xF, 0xF, 0));      \
    (V) = fmaxf((V), _o);                                                          \
}while(0)

// value-only max join via ds_swizzle xor pattern
#define VMAX_SWZ(V, PAT) do{                                                       \
    float _o = __int_as_float(__builtin_amdgcn_ds_swizzle(__float_as_int(V), PAT));\
    (V) = fmaxf((V), _o);                                                          \
}while(0)

__global__ __launch_bounds__(TPB, 4) void fps_kernel(const float* __restrict__ xyz,
                                                     int* __restrict__ idx_out)
{
    const int b = blockIdx.x;
    const int t = threadIdx.x;
    const int wid  = t >> 6;
    const int lane = t & 63;
    const float* xb = xyz + (size_t)b * 3 * N_;

    extern __shared__ float smem[];          // dynamic: coord cache
    float* cX = smem;
    float* cY = smem + NC;
    float* cZ = smem + 2 * NC;

    float px[PPT], py[PPT], pz[PPT], dist[PPT];

    // Load 16 consecutive points per thread (float4-vectorized, coalesced).
    {
        const float4* x4 = reinterpret_cast<const float4*>(xb);
        const float4* y4 = reinterpret_cast<const float4*>(xb + N_);
        const float4* z4 = reinterpret_cast<const float4*>(xb + 2 * N_);
        #pragma unroll
        for (int q = 0; q < 4; ++q) {
            float4 vx = x4[t * 4 + q];
            float4 vy = y4[t * 4 + q];
            float4 vz = z4[t * 4 + q];
            px[q*4+0] = vx.x; px[q*4+1] = vx.y; px[q*4+2] = vx.z; px[q*4+3] = vx.w;
            py[q*4+0] = vy.x; py[q*4+1] = vy.y; py[q*4+2] = vy.z; py[q*4+3] = vy.w;
            pz[q*4+0] = vz.x; pz[q*4+1] = vz.y; pz[q*4+2] = vz.z; pz[q*4+3] = vz.w;
        }
    }
    #pragma unroll
    for (int i = 0; i < PPT; ++i) dist[i] = 1e10f;  // BIG sentinel

    // Fill LDS coord cache (one-time; visible by first use via iter-1 barriers).
    for (int p = t; p < NC; p += TPB) {
        cX[p] = xb[p];
        cY[p] = xb[N_ + p];
        cZ[p] = xb[2 * N_ + p];
    }

    __shared__ float lv[4][16];   // per-wave value partials (4-ring)
    __shared__ int   widx[4];     // winning-index word per ring

    if (t < 4) widx[t] = 0x7fffffff;   // init rings; visible after B1(m=1)

    if (t == 0) idx_out[b * M_ + 0] = 0;   // deterministic start at index 0

    // First centroid = point 0.
    float cx = xb[0], cy = xb[N_], cz = xb[2 * N_];

    for (int m = 1; m < M_; ++m) {
        const int buf = m & 3;

        // ---- a: distance update (locked semantics) + value max (max3 pairs)
        float vmax = -1.0f;
        #pragma unroll
        for (int i = 0; i < PPT; i += 2) {
            float dx0 = __fsub_rn(px[i], cx);
            float dy0 = __fsub_rn(py[i], cy);
            float dz0 = __fsub_rn(pz[i], cz);
            float d0  = fmaf(dz0, dz0, fmaf(dx0, dx0, __fmul_rn(dy0, dy0)));
            float n0  = fminf(dist[i], d0);
            dist[i] = n0;
            float dx1 = __fsub_rn(px[i+1], cx);
            float dy1 = __fsub_rn(py[i+1], cy);
            float dz1 = __fsub_rn(pz[i+1], cz);
            float d1  = fmaf(dz1, dz1, fmaf(dx1, dx1, __fmul_rn(dy1, dy1)));
            float n1  = fminf(dist[i+1], d1);
            dist[i+1] = n1;
            vmax = fmaxf(fmaxf(vmax, n0), n1);   // fuses to v_max3_f32 (exact)
        }
        const float lmax = vmax;   // pre-reduce local max for match test

        // ---- b: wave value-reduce (4 DPP + xor16 swizzle + xor32 shfl)
        VMAX_DPP(vmax, DPP_QUAD_XOR1);
        VMAX_DPP(vmax, DPP_QUAD_XOR2);
        VMAX_DPP(vmax, DPP_HALF_MIRROR);
        VMAX_DPP(vmax, DPP_ROW_MIRROR);
        VMAX_SWZ(vmax, SWZ_XOR16);
        vmax = fmaxf(vmax, __shfl_xor(vmax, 32));

        // ---- c: publish wave partial; reset ring for iter m+2 (barrier-safe)
        if (lane == 0) lv[buf][wid] = vmax;
        if (t == 0) widx[(m + 2) & 3] = 0x7fffffff;
        __syncthreads();   // B1

        // ---- d: block value-reduce (16 partials, pure DPP within 16-lane row)
        float v2 = (lane < 16) ? lv[buf][lane] : -1.0f;
        VMAX_DPP(v2, DPP_QUAD_XOR1);
        VMAX_DPP(v2, DPP_QUAD_XOR2);
        VMAX_DPP(v2, DPP_HALF_MIRROR);
        VMAX_DPP(v2, DPP_ROW_MIRROR);
        const float bmax = __int_as_float(
            __builtin_amdgcn_readfirstlane(__float_as_int(v2)));

        // ---- e: rare index-find (only matching thread(s); waves skip via execz)
        if (lmax == bmax) {
            int cand = 0;
            #pragma unroll
            for (int i = PPT - 1; i >= 0; --i)      // descending: smallest slot wins
                cand = (dist[i] == bmax) ? i : cand;
            atomicMin(&widx[buf], t * PPT + cand);  // global MIN index (tie-break)
        }
        __syncthreads();   // B2

        // ---- f: read winner, emit, reload centroid (LDS-cached or VMEM)
        const int j = __builtin_amdgcn_readfirstlane(widx[buf]);
        if (t == 0) idx_out[b * M_ + m] = j;
        if (j < NC) {   // uniform scalar branch; ds_read broadcast (~70cyc)
            cx = cX[j];
            cy = cY[j];
            cz = cZ[j];
        } else {        // fallback: L2 loads (~200cyc), 34% of iterations
            cx = xb[j];
            cy = xb[N_ + j];
            cz = xb[2 * N_ + j];
        }
    }
}

// -------------------------------------------------------------------------
// Gather kernel: one block per (batch, output row). Rows 0..2 = xyz, 3..130 =
// feature channels. Raw f32 passthrough of gathered values.
// -------------------------------------------------------------------------
__global__ void gather_kernel(const float* __restrict__ xyz,
                              const float* __restrict__ feat,
                              const int*   __restrict__ idx,
                              float*       __restrict__ out)
{
    const int blk = blockIdx.x;
    const int b = blk / (3 + C_);
    const int r = blk % (3 + C_);
    const int* idb = idx + b * M_;

    if (r < 3) {
        const float* src = xyz + ((size_t)b * 3 + r) * N_;
        float*       dst = out + ((size_t)b * 3 + r) * M_;
        for (int m = threadIdx.x; m < M_; m += blockDim.x)
            dst[m] = src[idb[m]];
    } else {
        const int c = r - 3;
        const float* src = feat + ((size_t)b * C_ + c) * N_;
        float*       dst = out + (size_t)B_ * 3 * M_ + ((size_t)b * C_ + c) * M_;
        for (int m = threadIdx.x; m < M_; m += blockDim.x)
            dst[m] = src[idb[m]];
    }
}

extern "C" void kernel_launch(void* const* d_in, const int* in_sizes, int n_in,
                              void* d_out, int out_size, void* d_ws, size_t ws_size,
                              hipStream_t stream)
{
    const float* xyz  = (const float*)d_in[0];   // [16, 3, 16384] f32
    const float* feat = (const float*)d_in[1];   // [16, 128, 16384] f32
    float* out = (float*)d_out;                  // [16*3*4096] + [16*128*4096] f32
    int*   idx = (int*)d_ws;                     // [16, 4096] int32 scratch

    const size_t dyn_lds = (size_t)3 * NC * sizeof(float);   // 130560 B
    fps_kernel<<<dim3(B_), dim3(TPB), dyn_lds, stream>>>(xyz, idx);
    gather_kernel<<<dim3(B_ * (3 + C_)), dim3(256), 0, stream>>>(xyz, feat, idx, out);
}